// Round 1
// baseline (129.253 us; speedup 1.0000x reference)
//
#include <hip/hip_runtime.h>

#define BATCH 8
#define NH 6
#define HEAD_DIM 32
#define CCH 192
#define HH 56
#define WW 56
#define HWSZ (HH * WW)
#define KPOS 9
#define SCALE 0.17677669529663687f  // 32^-0.5

__global__ __launch_bounds__(256) void dilate_attn_kernel(
    const float* __restrict__ q,
    const float* __restrict__ k,
    const float* __restrict__ v,
    float* __restrict__ out)
{
    int tid = blockIdx.x * blockDim.x + threadIdx.x;
    if (tid >= BATCH * NH * HWSZ) return;

    int x  = tid % WW;
    int y  = (tid / WW) % HH;
    int bh = tid / HWSZ;          // b*NH + h
    int h  = bh % NH;
    int b  = bh / NH;

    const size_t chan_base = (size_t)(b * CCH + h * HEAD_DIM) * HWSZ;
    const float* qb = q + chan_base + y * WW + x;   // q[b, h*32 + d, y, x] at qb[d*HWSZ]
    const float* kb = k + chan_base;
    const float* vb = v + chan_base;

    // 9 dilated neighbor offsets + validity (zero padding)
    int  off[KPOS];
    bool ok[KPOS];
#pragma unroll
    for (int kk = 0; kk < KPOS; kk++) {
        int yy = y + 2 * (kk / 3) - 2;
        int xx = x + 2 * (kk % 3) - 2;
        bool good = (yy >= 0) & (yy < HH) & (xx >= 0) & (xx < WW);
        ok[kk]  = good;
        off[kk] = good ? (yy * WW + xx) : 0;
    }

    // ---- QK^T: attn[kk] = sum_d q[d] * k[d, kk] ----
    float attn[KPOS];
#pragma unroll
    for (int kk = 0; kk < KPOS; kk++) attn[kk] = 0.0f;

#pragma unroll 4
    for (int d = 0; d < HEAD_DIM; d++) {
        float qd = qb[(size_t)d * HWSZ];
        const float* kd = kb + (size_t)d * HWSZ;
#pragma unroll
        for (int kk = 0; kk < KPOS; kk++) {
            float kval = ok[kk] ? kd[off[kk]] : 0.0f;
            attn[kk] = fmaf(qd, kval, attn[kk]);
        }
    }

    // ---- softmax over the 9 positions (logits = dot * SCALE; OOB logit = 0) ----
    float m = attn[0] * SCALE;
#pragma unroll
    for (int kk = 0; kk < KPOS; kk++) {
        attn[kk] *= SCALE;
        m = fmaxf(m, attn[kk]);
    }
    float s = 0.0f;
#pragma unroll
    for (int kk = 0; kk < KPOS; kk++) {
        attn[kk] = __expf(attn[kk] - m);
        s += attn[kk];
    }
    float inv = 1.0f / s;
#pragma unroll
    for (int kk = 0; kk < KPOS; kk++) attn[kk] *= inv;

    // ---- PV: out[d] = sum_kk attn[kk] * v[d, kk]; contiguous 32-float store ----
    float* ob = out + ((size_t)((b * HH + y) * WW + x)) * CCH + h * HEAD_DIM;

#pragma unroll 2
    for (int d4 = 0; d4 < HEAD_DIM; d4 += 4) {
        float4 acc = make_float4(0.f, 0.f, 0.f, 0.f);
        const float* vd = vb + (size_t)d4 * HWSZ;
#pragma unroll
        for (int kk = 0; kk < KPOS; kk++) {
            if (ok[kk]) {
                const float* vp = vd + off[kk];
                acc.x = fmaf(attn[kk], vp[0 * HWSZ], acc.x);
                acc.y = fmaf(attn[kk], vp[1 * HWSZ], acc.y);
                acc.z = fmaf(attn[kk], vp[2 * HWSZ], acc.z);
                acc.w = fmaf(attn[kk], vp[3 * HWSZ], acc.w);
            }
        }
        *reinterpret_cast<float4*>(ob + d4) = acc;
    }
}

extern "C" void kernel_launch(void* const* d_in, const int* in_sizes, int n_in,
                              void* d_out, int out_size, void* d_ws, size_t ws_size,
                              hipStream_t stream) {
    const float* q = (const float*)d_in[0];
    const float* k = (const float*)d_in[1];
    const float* v = (const float*)d_in[2];
    float* out = (float*)d_out;

    const int total = BATCH * NH * HWSZ;      // 150528
    const int block = 256;
    const int grid  = (total + block - 1) / block;  // 588
    dilate_attn_kernel<<<grid, block, 0, stream>>>(q, k, v, out);
}